// Round 11
// baseline (20132.791 us; speedup 1.0000x reference)
//
#include <hip/hip_runtime.h>
#include <stdint.h>

typedef __attribute__((ext_vector_type(4))) float float4v;
typedef __attribute__((ext_vector_type(8))) short short8v;   // 8 x bf16 (4 VGPRs)

static __device__ __forceinline__ float sigp(float x){ return 1.f/(1.f+expf(-x)); }

// fp32 -> bf16 (RNE) and back
static __device__ __forceinline__ unsigned short f2bf(float x){
  unsigned u = __float_as_uint(x);
  u += 0x7FFFu + ((u>>16)&1u);
  return (unsigned short)(u>>16);
}
static __device__ __forceinline__ float bf2f(unsigned short h){
  return __uint_as_float(((unsigned)h)<<16);
}

static __device__ __forceinline__ void gload16(const void* g, void* l){
  __builtin_amdgcn_global_load_lds((const __attribute__((address_space(1))) void*)g,
                                   (__attribute__((address_space(3))) void*)l, 16, 0, 0);
}

__global__ void sentf_k(float* __restrict__ o, int n, float v){
  int i = blockIdx.x*256 + threadIdx.x; if (i < n) o[i] = v;
}

// ---------------- prep: plink + histogram over (seq, link) ----------------
__global__ void prep_k(const int* __restrict__ links, const int* __restrict__ paths,
                       const int* __restrict__ seqs, int* __restrict__ plink,
                       int* __restrict__ cnt){
  int e = blockIdx.x*256 + threadIdx.x;
  if (e < 120000){
    int p = paths[e], s = seqs[e], l = links[e];
    plink[p*6 + s] = l;
    atomicAdd(&cnt[s*2000 + l], 1);
  }
}
__global__ void scan_k(const int* __restrict__ cnt, int* __restrict__ off, int* __restrict__ cur){
  __shared__ int part[256]; __shared__ int pref[256];
  int t = threadIdx.x;
  int lo = t*47, hi = lo+47; if (hi > 12000) hi = 12000;
  int s = 0;
  for (int i=lo;i<hi;i++) s += cnt[i];
  part[t] = s; __syncthreads();
  if (t==0){ int r=0; for (int i=0;i<256;i++){ pref[i]=r; r+=part[i]; } }
  __syncthreads();
  int r = pref[t];
  for (int i=lo;i<hi;i++){ off[i]=r; cur[i]=r; r+=cnt[i]; }
}
__global__ void fill2_k(const int* __restrict__ links, const int* __restrict__ paths,
                        const int* __restrict__ seqs, int* __restrict__ cur,
                        int* __restrict__ plist){
  int e = blockIdx.x*256 + threadIdx.x;
  if (e < 120000){
    int p = paths[e], s = seqs[e], l = links[e];
    int pos = atomicAdd(&cur[s*2000 + l], 1);
    plist[pos] = p;
  }
}

// ---------------- weight split: W -> (hi, lo) bf16 ----------------
__global__ void wcvt_k(const float* __restrict__ W, unsigned short* __restrict__ hi,
                       unsigned short* __restrict__ lo, int n){
  int i = blockIdx.x*256 + threadIdx.x;
  if (i < n){
    float x = W[i];
    unsigned short h = f2bf(x);
    hi[i] = h;
    lo[i] = f2bf(x - bf2f(h));
  }
}

// ---------------- state init: hi/lo pairs into both ping-pong buffers ----------------
__global__ void initp_k(const float* __restrict__ x0,
                        unsigned short* __restrict__ h0, unsigned short* __restrict__ l0,
                        unsigned short* __restrict__ h1, unsigned short* __restrict__ l1,
                        int Mreal){
  int i = blockIdx.x*256 + threadIdx.x;   // grid covers Mp*512
  int m = i >> 9, c = i & 511;
  float v = (c==0 && m < Mreal) ? x0[m] : 0.f;
  unsigned short hh = f2bf(v);
  unsigned short ll = f2bf(v - bf2f(hh));
  h0[i]=hh; l0[i]=ll; h1[i]=hh; l1[i]=ll;
}

// ---------------- MFMA split-bf16 GEMM, optionally fused GRU step ----------------
// C[M,1536] = A[M,512] @ W[1536,512]^T  via  Ahi@Whi + Alo@Whi + Ahi@Wlo
// tile: BM=128, BN=192; 512 threads = 8 waves (wm 0..1, wn 0..3), wave tile 64x48.
// ROUND 11: 48 thin chunks, each staging ONE A-plane + ONE W-plane (20 KB):
//   kb 0..15:  Ahi x Whi;  kb 16..31: Alo x Whi;  kb 32..47: Ahi x Wlo.
//   Double-buffered = 40 KB LDS -> 4 blocks/CU x 8 waves = 8 waves/SIMD (was 2 blocks
//   at 80 KB). VGPR is cheap here (single-product chunk keeps 7 frags live) ->
//   __launch_bounds__(512,8) caps at 64 VGPR, matching round-10's measured count.
// XCD-aware flat grid (HW: XCD = bid % 8): A-slice + W L2-shared by 8 cb-siblings.
// gru=0: OutF[m*1536 + gcol] = acc + bias[gcol]
// gru=1: fused gates; state hi/lo in (Ahi,Alo) -> (Ohi,Olo); fp32 out only if writeF.
__global__ __launch_bounds__(512,8) void gmfma_k(
    const unsigned short* __restrict__ Ahi, const unsigned short* __restrict__ Alo,
    const unsigned short* __restrict__ Whi, const unsigned short* __restrict__ Wlo,
    const float* __restrict__ bias, const float* __restrict__ GI,
    const int* __restrict__ plink, int s,
    float* __restrict__ OutF,
    unsigned short* __restrict__ Ohi, unsigned short* __restrict__ Olo,
    int M, int gru, int writeF)
{
  // single-plane double buffers: 2 x (8 + 12) KB = 40 KB total
  __shared__ unsigned short sA0[128*32], sB0[192*32];
  __shared__ unsigned short sA1[128*32], sB1[192*32];
  const int tid  = threadIdx.x;
  const int lane = tid & 63, wave = tid >> 6;     // 0..7
  const int wm = wave >> 2, wn = wave & 3;        // wm 0..1, wn 0..3
  const int bid = blockIdx.x;
  const int X = bid & 7, kk2 = bid >> 3;
  const int m0 = ((kk2 >> 3)*8 + X) * 128;
  const int cb = kk2 & 7;
  const int c16 = lane & 15, kq = lane >> 4;

  // A staging: 512 granules (8 KB), one per thread. LDS granule g holds global
  // granule (row = g>>2, kg = (g&3) ^ ((row>>1)&3)) via pre-swizzled SOURCE.
  int offA;
  {
    int row = tid >> 2; int kg = (tid & 3) ^ ((row >> 1) & 3);
    offA = (m0 + row)*1024 + kg*16;
  }
  // B staging: 768 granules (12 KB); thread tid takes granule tid, tid<256 also 512+tid.
  // tile col v = wn_*48 + g*16 + c  ->  W row g*512 + cb*64 + wn_*16 + c.
  int offB0, offB1;
  {
    int gb = tid;
    int v  = gb >> 2;
    int kg = (gb & 3) ^ ((v >> 1) & 3);
    int wn_ = v / 48; int rem = v - wn_*48;
    int gg = rem >> 4, cc = rem & 15;
    offB0 = (gg*512 + cb*64 + wn_*16 + cc)*1024 + kg*16;
    gb = 512 + tid;                    // only meaningful for tid < 256
    v  = gb >> 2;
    kg = (gb & 3) ^ ((v >> 1) & 3);
    int wn2 = v / 48; rem = v - wn2*48;
    gg = rem >> 4; cc = rem & 15;
    if (wn2 > 3) wn2 = 3;
    offB1 = (gg*512 + cb*64 + wn2*16 + cc)*1024 + kg*16;
  }
  const int gA  = (wave*64)*8;
  const int gB0 = (wave*64)*8, gB1 = (512 + wave*64)*8;

  // ds_read base offsets (shorts); swizzle bits invariant under 16-row/col frag steps
  const int rA = wm*64 + c16;
  const int rdA = (rA*4 + (kq ^ ((rA>>1)&3)))*8;
  const int vB = wn*48 + c16;
  const int rdB = (vB*4 + (kq ^ ((vB>>1)&3)))*8;

  float4v acc[4][3];
#pragma unroll
  for (int i = 0; i < 4; ++i)
#pragma unroll
    for (int j = 0; j < 3; ++j) acc[i][j] = (float4v){0.f,0.f,0.f,0.f};

  // chunk kb (0..47): segment-select plane pair; k-slice = (kb & 15)
  auto STAGE = [&](int kb, unsigned short* dA, unsigned short* dB){
    const unsigned short* As = (kb >= 16 && kb < 32) ? Alo : Ahi;
    const unsigned short* Ws = (kb >= 32) ? Wlo : Whi;
    const int kbb = (kb & 15)*64;          // 32 k-elems * 2B
    const char* ap = (const char*)As + kbb;
    const char* wp = (const char*)Ws + kbb;
    gload16(ap + offA, dA + gA);
    gload16(wp + offB0, dB + gB0);
    if (tid < 256){                        // wave-uniform (waves 0..3)
      gload16(wp + offB1, dB + gB1);
    }
  };

  auto COMPUTE = [&](const unsigned short* tA, const unsigned short* tB){
    short8v a[4], b[3];
#pragma unroll
    for (int mf = 0; mf < 4; ++mf) a[mf] = *(const short8v*)(tA + rdA + mf*512);
#pragma unroll
    for (int g = 0; g < 3; ++g)  b[g]  = *(const short8v*)(tB + rdB + g*512);
#pragma unroll
    for (int mf = 0; mf < 4; ++mf)
#pragma unroll
      for (int g = 0; g < 3; ++g)
        acc[mf][g] = __builtin_amdgcn_mfma_f32_16x16x32_bf16(a[mf], b[g], acc[mf][g], 0, 0, 0);
  };

  STAGE(0, sA0, sB0);
  __syncthreads();                         // buf0 ready
  for (int q = 0; q < 24; ++q){
    STAGE(2*q+1, sA1, sB1);                // prefetch odd chunk into buf1
    COMPUTE(sA0, sB0);                     // compute even chunk from buf0
    __syncthreads();                       // drains prefetch; buf1 ready
    if (q < 23) STAGE(2*q+2, sA0, sB0);    // prefetch next even into buf0
    COMPUTE(sA1, sB1);
    __syncthreads();
  }

  // epilogue. C/D frag: col = lane&15, row = (lane>>4)*4 + reg.
  const int col = cb*64 + wn*16 + c16;
  if (!gru){
    const float b0f = bias[col], b1f = bias[512+col], b2f = bias[1024+col];
#pragma unroll
    for (int mf = 0; mf < 4; ++mf){
      const int mb = m0 + wm*64 + mf*16 + kq*4;
#pragma unroll
      for (int r = 0; r < 4; ++r){
        const int m = mb + r;
        if (m < M){
          float* c = OutF + (size_t)m*1536 + col;
          c[0]    = acc[mf][0][r] + b0f;
          c[512]  = acc[mf][1][r] + b1f;
          c[1024] = acc[mf][2][r] + b2f;
        }
      }
    }
  } else {
    const float br = bias[col], bz = bias[512+col], bn = bias[1024+col];
#pragma unroll
    for (int mf = 0; mf < 4; ++mf){
      const int mb = m0 + wm*64 + mf*16 + kq*4;
#pragma unroll
      for (int r = 0; r < 4; ++r){
        const int m = mb + r;
        if (m < M){
          const int gr = plink ? plink[m*6 + s] : m;
          const float* gi = GI + (size_t)gr*1536 + col;
          const size_t ix = (size_t)m*512 + col;
          float hold = bf2f(Ahi[ix]) + bf2f(Alo[ix]);
          float rr = sigp(gi[0]    + acc[mf][0][r] + br);
          float zz = sigp(gi[512]  + acc[mf][1][r] + bz);
          float nn = 2.f*sigp(2.f*(gi[1024] + rr*(acc[mf][2][r] + bn))) - 1.f; // tanh
          float h  = (1.f - zz)*nn + zz*hold;
          unsigned short hh = f2bf(h);
          Ohi[ix] = hh;
          Olo[ix] = f2bf(h - bf2f(hh));
          if (writeF) OutF[ix] = h;
        }
      }
    }
  }
}

// ---------------- readout MFMA GEMM: C[M,N] = relu?(Apair @ Wpair^T + b) ----------------
// 256 threads = 4 waves (wm=wave>>1, wn=wave&1), wave tile 64x32 (mf=4, nf=2).
__global__ __launch_bounds__(256,3) void rgemm_k(
    const unsigned short* __restrict__ Ahi, const unsigned short* __restrict__ Alo,
    const unsigned short* __restrict__ Whi, const unsigned short* __restrict__ Wlo,
    const float* __restrict__ bias,
    float* __restrict__ OutF,
    unsigned short* __restrict__ Ohi, unsigned short* __restrict__ Olo,
    int M, int N, int K, int relu)
{
  __shared__ unsigned short rAh0[128*32], rAl0[128*32], rWh0[64*32], rWl0[64*32];
  __shared__ unsigned short rAh1[128*32], rAl1[128*32], rWh1[64*32], rWl1[64*32];
  const int tid = threadIdx.x;
  const int lane = tid & 63, wave = tid >> 6;
  const int wm = wave >> 1, wn = wave & 1;
  const int m0 = blockIdx.x * 128, n0 = blockIdx.y * 64;
  const int c16 = lane & 15, kq = lane >> 4;
  const int K2 = K*2;

  int offA0, offA1, offW;
  { int g = tid;      int row = g>>2; int kg=(g&3)^((row>>1)&3); offA0 = (m0+row)*K2 + kg*16; }
  { int g = tid+256;  int row = g>>2; int kg=(g&3)^((row>>1)&3); offA1 = (m0+row)*K2 + kg*16; }
  { int g = tid;      int v = g>>2;   int kg=(g&3)^((v>>1)&3);   offW  = (n0+v)*K2 + kg*16; }
  const int gA0 = (wave*64)*8, gA1 = (wave*64+256)*8;
  const int gW  = (wave*64)*8;

  const int rA = wm*64 + c16;
  const int rdA = (rA*4 + (kq ^ ((rA>>1)&3)))*8;
  const int vB = wn*32 + c16;
  const int rdB = (vB*4 + (kq ^ ((vB>>1)&3)))*8;

  float4v acc[4][2];
#pragma unroll
  for (int i = 0; i < 4; ++i)
#pragma unroll
    for (int j = 0; j < 2; ++j) acc[i][j] = (float4v){0.f,0.f,0.f,0.f};

  auto STAGE = [&](int kb, unsigned short* dAh, unsigned short* dAl,
                   unsigned short* dWh, unsigned short* dWl){
    const int kbb = kb*64;
    gload16((const char*)Ahi + kbb + offA0, dAh + gA0);
    gload16((const char*)Ahi + kbb + offA1, dAh + gA1);
    gload16((const char*)Alo + kbb + offA0, dAl + gA0);
    gload16((const char*)Alo + kbb + offA1, dAl + gA1);
    gload16((const char*)Whi + kbb + offW, dWh + gW);
    gload16((const char*)Wlo + kbb + offW, dWl + gW);
  };

  auto COMPUTE = [&](const unsigned short* tAh, const unsigned short* tAl,
                     const unsigned short* tWh, const unsigned short* tWl){
    short8v ah[4], al[4], bh[2], bl[2];
#pragma unroll
    for (int mf = 0; mf < 4; ++mf) ah[mf] = *(const short8v*)(tAh + rdA + mf*512);
#pragma unroll
    for (int nf = 0; nf < 2; ++nf) bh[nf] = *(const short8v*)(tWh + rdB + nf*512);
#pragma unroll
    for (int mf = 0; mf < 4; ++mf) al[mf] = *(const short8v*)(tAl + rdA + mf*512);
#pragma unroll
    for (int mf = 0; mf < 4; ++mf)
#pragma unroll
      for (int nf = 0; nf < 2; ++nf)
        acc[mf][nf] = __builtin_amdgcn_mfma_f32_16x16x32_bf16(ah[mf], bh[nf], acc[mf][nf], 0, 0, 0);
#pragma unroll
    for (int nf = 0; nf < 2; ++nf) bl[nf] = *(const short8v*)(tWl + rdB + nf*512);
#pragma unroll
    for (int mf = 0; mf < 4; ++mf)
#pragma unroll
      for (int nf = 0; nf < 2; ++nf)
        acc[mf][nf] = __builtin_amdgcn_mfma_f32_16x16x32_bf16(al[mf], bh[nf], acc[mf][nf], 0, 0, 0);
#pragma unroll
    for (int mf = 0; mf < 4; ++mf)
#pragma unroll
      for (int nf = 0; nf < 2; ++nf)
        acc[mf][nf] = __builtin_amdgcn_mfma_f32_16x16x32_bf16(ah[mf], bl[nf], acc[mf][nf], 0, 0, 0);
  };

  const int nc = K >> 5;                    // chunks of 32 (16 for K=512, 8 for K=256)
  STAGE(0, rAh0, rAl0, rWh0, rWl0);
  __syncthreads();
  for (int q = 0; q < (nc>>1); ++q){
    STAGE(2*q+1, rAh1, rAl1, rWh1, rWl1);
    COMPUTE(rAh0, rAl0, rWh0, rWl0);
    __syncthreads();
    if (q < (nc>>1)-1) STAGE(2*q+2, rAh0, rAl0, rWh0, rWl0);
    COMPUTE(rAh1, rAl1, rWh1, rWl1);
    __syncthreads();
  }

  // epilogue
#pragma unroll
  for (int nf = 0; nf < 2; ++nf){
    const int col = n0 + wn*32 + nf*16 + c16;
    const float b = bias[col];
#pragma unroll
    for (int mf = 0; mf < 4; ++mf){
      const int mb = m0 + wm*64 + mf*16 + kq*4;
#pragma unroll
      for (int r = 0; r < 4; ++r){
        const int m = mb + r;
        if (m < M){
          float v = acc[mf][nf][r] + b;
          if (relu) v = fmaxf(v, 0.f);
          const size_t ix = (size_t)m*N + col;
          if (OutF) OutF[ix] = v;
          if (Ohi){
            unsigned short hh = f2bf(v);
            Ohi[ix] = hh;
            Olo[ix] = f2bf(v - bf2f(hh));
          }
        }
      }
    }
  }
}

// ---------------- per-step segment-sum (u32-vectorized); emits hi/lo agg at s==5 ----------------
__global__ void aggv_k(const unsigned short* __restrict__ Hh, const unsigned short* __restrict__ Hl,
                       const int* __restrict__ plist,
                       const int* __restrict__ off, const int* __restrict__ cnt, int s,
                       float* __restrict__ AGG, int isFirst,
                       unsigned short* __restrict__ Ghi, unsigned short* __restrict__ Glo,
                       int emit)
{
  int l = blockIdx.x, t = threadIdx.x;        // thread t handles cols 2t, 2t+1
  size_t base = (size_t)l*512 + 2*t;
  if (l >= 2000){
    AGG[base] = 0.f; AGG[base+1] = 0.f;
    if (emit){ *(unsigned*)&Ghi[base] = 0u; *(unsigned*)&Glo[base] = 0u; }
    return;
  }
  int o = off[s*2000 + l], c = cnt[s*2000 + l];
  float a0 = isFirst ? 0.f : AGG[base];
  float a1 = isFirst ? 0.f : AGG[base+1];
  for (int i = 0; i < c; ++i){
    size_t p = (size_t)plist[o + i] * 512 + 2*t;
    unsigned hh = *(const unsigned*)(Hh + p);
    unsigned hl = *(const unsigned*)(Hl + p);
    a0 += __uint_as_float(hh << 16) + __uint_as_float(hl << 16);
    a1 += __uint_as_float(hh & 0xffff0000u) + __uint_as_float(hl & 0xffff0000u);
  }
  AGG[base] = a0; AGG[base+1] = a1;
  if (emit){
    unsigned short h0 = f2bf(a0), h1 = f2bf(a1);
    *(unsigned*)&Ghi[base] = (unsigned)h0 | ((unsigned)h1 << 16);
    unsigned short l0 = f2bf(a0 - bf2f(h0)), l1 = f2bf(a1 - bf2f(h1));
    *(unsigned*)&Glo[base] = (unsigned)l0 | ((unsigned)l1 << 16);
  }
}

// ---------------- final 128->1 dot per row ----------------
__global__ void dotf_k(const float* __restrict__ T2, const float* __restrict__ w3,
                       const float* __restrict__ b3, float* __restrict__ out, int M)
{
  int lane = threadIdx.x & 63, w = threadIdx.x >> 6;
  int m = blockIdx.x * 4 + w;
  if (m >= M) return;
  float s = T2[(size_t)m*128 + lane] * w3[lane]
          + T2[(size_t)m*128 + 64 + lane] * w3[64 + lane];
#pragma unroll
  for (int off = 32; off; off >>= 1) s += __shfl_xor(s, off);
  if (lane == 0) out[m] = s + b3[0];
}

extern "C" void kernel_launch(void* const* d_in, const int* in_sizes, int n_in,
                              void* d_out, int out_size, void* d_ws, size_t ws_size,
                              hipStream_t stream)
{
  const int*   links = (const int*)d_in[0];
  const int*   paths = (const int*)d_in[1];
  const int*   seqs  = (const int*)d_in[2];
  const float* cap   = (const float*)d_in[3];
  const float* bw    = (const float*)d_in[4];
  const float* Wih_p = (const float*)d_in[5];
  const float* Whh_p = (const float*)d_in[6];
  const float* bih_p = (const float*)d_in[7];
  const float* bhh_p = (const float*)d_in[8];
  const float* Wih_l = (const float*)d_in[9];
  const float* Whh_l = (const float*)d_in[10];
  const float* bih_l = (const float*)d_in[11];
  const float* bhh_l = (const float*)d_in[12];
  const float* d_w1 = (const float*)d_in[13]; const float* d_b1 = (const float*)d_in[14];
  const float* d_w2 = (const float*)d_in[15]; const float* d_b2 = (const float*)d_in[16];
  const float* d_w3 = (const float*)d_in[17]; const float* d_b3 = (const float*)d_in[18];
  const float* j_w1 = (const float*)d_in[19]; const float* j_b1 = (const float*)d_in[20];
  const float* j_w2 = (const float*)d_in[21]; const float* j_b2 = (const float*)d_in[22];
  const float* j_w3 = (const float*)d_in[23]; const float* j_b3 = (const float*)d_in[24];
  float* out = (float*)d_out;

  const int MpP = 20480;   // 160 * 128 (XCD mapping total: 20 m-blocks/XCD)
  const int MpL = 2048;    // 16 * 128
  char* p = (char*)d_ws;
  auto alloc = [&](size_t n){ char* r = p; p += (n + 255) & ~(size_t)255; return r; };
  unsigned short* Phi[2]; unsigned short* Plo[2];
  Phi[0] = (unsigned short*)alloc((size_t)MpP*512*2);
  Plo[0] = (unsigned short*)alloc((size_t)MpP*512*2);
  Phi[1] = (unsigned short*)alloc((size_t)MpP*512*2);
  Plo[1] = (unsigned short*)alloc((size_t)MpP*512*2);
  unsigned short* Lhi[2]; unsigned short* Llo[2];
  Lhi[0] = (unsigned short*)alloc((size_t)MpL*512*2);
  Llo[0] = (unsigned short*)alloc((size_t)MpL*512*2);
  Lhi[1] = (unsigned short*)alloc((size_t)MpL*512*2);
  Llo[1] = (unsigned short*)alloc((size_t)MpL*512*2);
  float* LG  = (float*)alloc((size_t)MpL*1536*4);                // gi rows [2048,1536]
  float* AGG = (float*)alloc((size_t)MpL*512*4);
  unsigned short* AGh = (unsigned short*)alloc((size_t)MpL*512*2);
  unsigned short* AGl = (unsigned short*)alloc((size_t)MpL*512*2);
  unsigned short* WhhPh = (unsigned short*)alloc((size_t)1536*512*2);
  unsigned short* WhhPl = (unsigned short*)alloc((size_t)1536*512*2);
  unsigned short* WihPh = (unsigned short*)alloc((size_t)1536*512*2);
  unsigned short* WihPl = (unsigned short*)alloc((size_t)1536*512*2);
  unsigned short* WhhLh = (unsigned short*)alloc((size_t)1536*512*2);
  unsigned short* WhhLl = (unsigned short*)alloc((size_t)1536*512*2);
  unsigned short* WihLh = (unsigned short*)alloc((size_t)1536*512*2);
  unsigned short* WihLl = (unsigned short*)alloc((size_t)1536*512*2);
  unsigned short* DW1h = (unsigned short*)alloc((size_t)256*512*2);
  unsigned short* DW1l = (unsigned short*)alloc((size_t)256*512*2);
  unsigned short* DW2h = (unsigned short*)alloc((size_t)128*256*2);
  unsigned short* DW2l = (unsigned short*)alloc((size_t)128*256*2);
  unsigned short* JW1h = (unsigned short*)alloc((size_t)256*512*2);
  unsigned short* JW1l = (unsigned short*)alloc((size_t)256*512*2);
  unsigned short* JW2h = (unsigned short*)alloc((size_t)128*256*2);
  unsigned short* JW2l = (unsigned short*)alloc((size_t)128*256*2);
  int* cnt2  = (int*)alloc(12000*4);
  int* off2  = (int*)alloc(12000*4);
  int* cur2  = (int*)alloc(12000*4);
  int* plist = (int*)alloc(120000*4);
  int* plink = (int*)alloc(120000*4);
  // readout scratch aliases dead buffers after the loop (final state pair = Phi[0]/Plo[0]):
  unsigned short* t1h = Phi[1];   // [20096,256] bf16 -> 10.29 MB <= 20.97 MB
  unsigned short* t1l = Plo[1];
  float* t2 = LG;                 // [20032,128] fp32 -> 10.26 MB <= 12.58 MB
  if ((size_t)(p - (char*)d_ws) > ws_size){
    sentf_k<<<(out_size+255)/256,256,0,stream>>>(out, out_size, 0.25f);
    return;
  }

  hipMemsetAsync(cnt2, 0, 12000*4, stream);
  prep_k<<<469,256,0,stream>>>(links, paths, seqs, plink, cnt2);
  scan_k<<<1,256,0,stream>>>(cnt2, off2, cur2);
  fill2_k<<<469,256,0,stream>>>(links, paths, seqs, cur2, plist);
  wcvt_k<<<3072,256,0,stream>>>(Whh_p, WhhPh, WhhPl, 1536*512);
  wcvt_k<<<3072,256,0,stream>>>(Wih_p, WihPh, WihPl, 1536*512);
  wcvt_k<<<3072,256,0,stream>>>(Whh_l, WhhLh, WhhLl, 1536*512);
  wcvt_k<<<3072,256,0,stream>>>(Wih_l, WihLh, WihLl, 1536*512);
  wcvt_k<<<512,256,0,stream>>>(d_w1, DW1h, DW1l, 256*512);
  wcvt_k<<<128,256,0,stream>>>(d_w2, DW2h, DW2l, 128*256);
  wcvt_k<<<512,256,0,stream>>>(j_w1, JW1h, JW1l, 256*512);
  wcvt_k<<<128,256,0,stream>>>(j_w2, JW2h, JW2l, 128*256);
  initp_k<<<(MpP*512)/256,256,0,stream>>>(bw,  Phi[0], Plo[0], Phi[1], Plo[1], 20000);
  initp_k<<<(MpL*512)/256,256,0,stream>>>(cap, Lhi[0], Llo[0], Lhi[1], Llo[1], 2000);

  int pb = 0, lb = 0;
  for (int t = 0; t < 8; ++t) {
    // LG = link_h @ Wih_p^T + bih_p  (gi rows for path entries)
    gmfma_k<<<16*8,512,0,stream>>>(Lhi[lb], Llo[lb], WihPh, WihPl, bih_p,
                                   (const float*)0, (const int*)0, 0,
                                   LG, (unsigned short*)0, (unsigned short*)0, 2000, 0, 0);
    for (int s6 = 0; s6 < 6; ++s6) {
      gmfma_k<<<160*8,512,0,stream>>>(Phi[pb], Plo[pb], WhhPh, WhhPl, bhh_p,
                                      LG, plink, s6,
                                      (float*)0, Phi[pb^1], Plo[pb^1], 20000, 1, 0);
      pb ^= 1;
      aggv_k<<<2048,256,0,stream>>>(Phi[pb], Plo[pb], plist, off2, cnt2, s6, AGG,
                                    (s6==0)?1:0, AGh, AGl, (s6==5)?1:0);
    }
    // GIL = agg @ Wih_l^T + bih_l (into LG); link_h = GRU(GIL, link_h)
    gmfma_k<<<16*8,512,0,stream>>>(AGh, AGl, WihLh, WihLl, bih_l,
                                   (const float*)0, (const int*)0, 0,
                                   LG, (unsigned short*)0, (unsigned short*)0, 2000, 0, 0);
    gmfma_k<<<16*8,512,0,stream>>>(Lhi[lb], Llo[lb], WhhLh, WhhLl, bhh_l,
                                   LG, (const int*)0, 0,
                                   (float*)0, Lhi[lb^1], Llo[lb^1], 2000, 1, 0);
    lb ^= 1;
  }
  // final state pair: pb flipped 48 times -> Phi[0]/Plo[0]

  // readout: delay (MFMA split-bf16; layer1 emits t1 pair, layer2 emits fp32 t2)
  rgemm_k<<<dim3(157,4),256,0,stream>>>(Phi[0], Plo[0], DW1h, DW1l, d_b1,
                                        (float*)0, t1h, t1l, 20000, 256, 512, 1);
  rgemm_k<<<dim3(157,2),256,0,stream>>>(t1h, t1l, DW2h, DW2l, d_b2,
                                        t2, (unsigned short*)0, (unsigned short*)0, 20000, 128, 256, 1);
  dotf_k<<<5000,256,0,stream>>>(t2, d_w3, d_b3, out, 20000);
  // readout: jitter
  rgemm_k<<<dim3(157,4),256,0,stream>>>(Phi[0], Plo[0], JW1h, JW1l, j_b1,
                                        (float*)0, t1h, t1l, 20000, 256, 512, 1);
  rgemm_k<<<dim3(157,2),256,0,stream>>>(t1h, t1l, JW2h, JW2l, j_b2,
                                        t2, (unsigned short*)0, (unsigned short*)0, 20000, 128, 256, 1);
  dotf_k<<<5000,256,0,stream>>>(t2, j_w3, j_b3, out + 20000, 20000);
}

// Round 12
// 10058.503 us; speedup vs baseline: 2.0016x; 2.0016x over previous
//
#include <hip/hip_runtime.h>
#include <stdint.h>

typedef __attribute__((ext_vector_type(4))) float float4v;
typedef __attribute__((ext_vector_type(8))) short short8v;   // 8 x bf16 (4 VGPRs)

static __device__ __forceinline__ float sigp(float x){ return 1.f/(1.f+expf(-x)); }

// fp32 -> bf16 (RNE) and back
static __device__ __forceinline__ unsigned short f2bf(float x){
  unsigned u = __float_as_uint(x);
  u += 0x7FFFu + ((u>>16)&1u);
  return (unsigned short)(u>>16);
}
static __device__ __forceinline__ float bf2f(unsigned short h){
  return __uint_as_float(((unsigned)h)<<16);
}

static __device__ __forceinline__ void gload16(const void* g, void* l){
  __builtin_amdgcn_global_load_lds((const __attribute__((address_space(1))) void*)g,
                                   (__attribute__((address_space(3))) void*)l, 16, 0, 0);
}

__global__ void sentf_k(float* __restrict__ o, int n, float v){
  int i = blockIdx.x*256 + threadIdx.x; if (i < n) o[i] = v;
}

// ---------------- prep: plink + histogram over (seq, link) ----------------
__global__ void prep_k(const int* __restrict__ links, const int* __restrict__ paths,
                       const int* __restrict__ seqs, int* __restrict__ plink,
                       int* __restrict__ cnt){
  int e = blockIdx.x*256 + threadIdx.x;
  if (e < 120000){
    int p = paths[e], s = seqs[e], l = links[e];
    plink[p*6 + s] = l;
    atomicAdd(&cnt[s*2000 + l], 1);
  }
}
__global__ void scan_k(const int* __restrict__ cnt, int* __restrict__ off, int* __restrict__ cur){
  __shared__ int part[256]; __shared__ int pref[256];
  int t = threadIdx.x;
  int lo = t*47, hi = lo+47; if (hi > 12000) hi = 12000;
  int s = 0;
  for (int i=lo;i<hi;i++) s += cnt[i];
  part[t] = s; __syncthreads();
  if (t==0){ int r=0; for (int i=0;i<256;i++){ pref[i]=r; r+=part[i]; } }
  __syncthreads();
  int r = pref[t];
  for (int i=lo;i<hi;i++){ off[i]=r; cur[i]=r; r+=cnt[i]; }
}
__global__ void fill2_k(const int* __restrict__ links, const int* __restrict__ paths,
                        const int* __restrict__ seqs, int* __restrict__ cur,
                        int* __restrict__ plist){
  int e = blockIdx.x*256 + threadIdx.x;
  if (e < 120000){
    int p = paths[e], s = seqs[e], l = links[e];
    int pos = atomicAdd(&cur[s*2000 + l], 1);
    plist[pos] = p;
  }
}

// ---------------- weight split: W -> (hi, lo) bf16 ----------------
__global__ void wcvt_k(const float* __restrict__ W, unsigned short* __restrict__ hi,
                       unsigned short* __restrict__ lo, int n){
  int i = blockIdx.x*256 + threadIdx.x;
  if (i < n){
    float x = W[i];
    unsigned short h = f2bf(x);
    hi[i] = h;
    lo[i] = f2bf(x - bf2f(h));
  }
}

// ---------------- state init: hi/lo pairs into both ping-pong buffers ----------------
__global__ void initp_k(const float* __restrict__ x0,
                        unsigned short* __restrict__ h0, unsigned short* __restrict__ l0,
                        unsigned short* __restrict__ h1, unsigned short* __restrict__ l1,
                        int Mreal){
  int i = blockIdx.x*256 + threadIdx.x;   // grid covers Mp*512
  int m = i >> 9, c = i & 511;
  float v = (c==0 && m < Mreal) ? x0[m] : 0.f;
  unsigned short hh = f2bf(v);
  unsigned short ll = f2bf(v - bf2f(hh));
  h0[i]=hh; l0[i]=ll; h1[i]=hh; l1[i]=ll;
}

// ---------------- MFMA split-bf16 GEMM, optionally fused GRU step ----------------
// (round-10 verified structure + LDS hold-harvest; template MF: BM = MF*32)
// C[M,1536] = A[M,512] @ W[1536,512]^T  via  Ahi@Whi + Alo@Whi + Ahi@Wlo
// tile: BM x 192; 512 threads = 8 waves (wm 0..1, wn 0..3), wave tile (MF*16) x 48.
// MF=4 (path, BM=128, grid nmb*8=1280) -- byte-identical math to round 10.
// MF=2 (link, BM=64, grid 32*8=256) -- doubles link-side parallelism.
// hold-harvest: epilogue's hold = Ahi[m][col]+Alo[m][col]; col's k-chunk (col>>5,
// wave-uniform) passes through LDS during the K-loop -> 32 scalar ds_reads right
// after that chunk's COMPUTE (before the barrier preceding buffer overwrite)
// replace the 42 MB global hold re-read. Bit-identical values.
// gru=0: OutF[m*1536 + gcol] = acc + bias[gcol]
// gru=1: fused gates; state hi/lo in (Ahi,Alo) -> (Ohi,Olo); fp32 out only if writeF.
template<int MF>
__global__ __launch_bounds__(512,4) void gmfma_t(
    const unsigned short* __restrict__ Ahi, const unsigned short* __restrict__ Alo,
    const unsigned short* __restrict__ Whi, const unsigned short* __restrict__ Wlo,
    const float* __restrict__ bias, const float* __restrict__ GI,
    const int* __restrict__ plink, int s,
    float* __restrict__ OutF,
    unsigned short* __restrict__ Ohi, unsigned short* __restrict__ Olo,
    int M, int gru, int writeF)
{
  __shared__ unsigned short sAh0[MF*1024], sAl0[MF*1024];
  __shared__ unsigned short sBh0[192*32], sBl0[192*32];
  __shared__ unsigned short sAh1[MF*1024], sAl1[MF*1024];
  __shared__ unsigned short sBh1[192*32], sBl1[192*32];
  const int tid  = threadIdx.x;
  const int lane = tid & 63, wave = tid >> 6;     // 0..7
  const int wm = wave >> 2, wn = wave & 3;        // wm 0..1, wn 0..3
  const int bid = blockIdx.x;
  const int X = bid & 7, kk2 = bid >> 3;
  const int m0 = ((kk2 >> 3)*8 + X) * (MF*32);
  const int cb = kk2 & 7;
  const int c16 = lane & 15, kq = lane >> 4;

  // A staging: BM*4 = MF*128 granules, one per thread (threads >= MF*128 skip).
  // LDS granule g holds global granule (row=g>>2, kg=(g&3)^((row>>1)&3)) via
  // pre-swizzled SOURCE address.
  int offA = 0;
  if (tid < MF*128){
    int row = tid >> 2; int kg = (tid & 3) ^ ((row >> 1) & 3);
    offA = (m0 + row)*1024 + kg*16;
  }
  // B staging: 768 granules; thread tid takes granule tid, tid<256 also 512+tid.
  // tile col v = wn_*48 + g*16 + c  ->  W row g*512 + cb*64 + wn_*16 + c.
  int offB0, offB1;
  {
    int gb = tid;
    int v  = gb >> 2;
    int kg = (gb & 3) ^ ((v >> 1) & 3);
    int wn_ = v / 48; int rem = v - wn_*48;
    int gg = rem >> 4, cc = rem & 15;
    offB0 = (gg*512 + cb*64 + wn_*16 + cc)*1024 + kg*16;
    gb = 512 + tid;                    // only meaningful for tid < 256
    v  = gb >> 2;
    kg = (gb & 3) ^ ((v >> 1) & 3);
    int wn2 = v / 48; rem = v - wn2*48;
    gg = rem >> 4; cc = rem & 15;
    if (wn2 > 3) wn2 = 3;
    offB1 = (gg*512 + cb*64 + wn2*16 + cc)*1024 + kg*16;
  }
  const int gA  = (wave*64)*8;
  const int gB0 = (wave*64)*8, gB1 = (512 + wave*64)*8;

  // ds_read base offsets (shorts); swizzle bits invariant under 16-row/col frag steps
  const int rA = wm*(MF*16) + c16;
  const int rdA = (rA*4 + (kq ^ ((rA>>1)&3)))*8;
  const int vB = wn*48 + c16;
  const int rdB = (vB*4 + (kq ^ ((vB>>1)&3)))*8;

  // epilogue column and its A-chunk (wave-uniform: (wn*16+c16)>>5 == (wn>=2))
  const int col = cb*64 + wn*16 + c16;
  const int mychunk = col >> 5;          // in 0..15

  float4v acc[MF][3];
#pragma unroll
  for (int i = 0; i < MF; ++i)
#pragma unroll
    for (int j = 0; j < 3; ++j) acc[i][j] = (float4v){0.f,0.f,0.f,0.f};

  float hold[MF][4];
#pragma unroll
  for (int i = 0; i < MF; ++i)
#pragma unroll
    for (int r = 0; r < 4; ++r) hold[i][r] = 0.f;

  auto STAGE = [&](int kb, unsigned short* dAh, unsigned short* dAl,
                   unsigned short* dBh, unsigned short* dBl){
    const int kbb = kb*64;                 // 32 k-elems * 2B
    const char* ah = (const char*)Ahi + kbb;
    const char* al = (const char*)Alo + kbb;
    const char* wh = (const char*)Whi + kbb;
    const char* wl = (const char*)Wlo + kbb;
    if (tid < MF*128){
      gload16(ah + offA, dAh + gA);
      gload16(al + offA, dAl + gA);
    }
    gload16(wh + offB0, dBh + gB0);
    gload16(wl + offB0, dBl + gB0);
    if (tid < 256){                        // wave-uniform (waves 0..3)
      gload16(wh + offB1, dBh + gB1);
      gload16(wl + offB1, dBl + gB1);
    }
  };

  auto COMPUTE = [&](const unsigned short* tAh, const unsigned short* tAl,
                     const unsigned short* tBh, const unsigned short* tBl){
    short8v ah[MF], al[MF], bh[3], bl[3];
#pragma unroll
    for (int mf = 0; mf < MF; ++mf) ah[mf] = *(const short8v*)(tAh + rdA + mf*512);
#pragma unroll
    for (int g = 0; g < 3; ++g)  bh[g]  = *(const short8v*)(tBh + rdB + g*512);
#pragma unroll
    for (int mf = 0; mf < MF; ++mf) al[mf] = *(const short8v*)(tAl + rdA + mf*512);
#pragma unroll
    for (int mf = 0; mf < MF; ++mf)
#pragma unroll
      for (int g = 0; g < 3; ++g)
        acc[mf][g] = __builtin_amdgcn_mfma_f32_16x16x32_bf16(ah[mf], bh[g], acc[mf][g], 0, 0, 0);
#pragma unroll
    for (int g = 0; g < 3; ++g)  bl[g]  = *(const short8v*)(tBl + rdB + g*512);
#pragma unroll
    for (int mf = 0; mf < MF; ++mf)
#pragma unroll
      for (int g = 0; g < 3; ++g)
        acc[mf][g] = __builtin_amdgcn_mfma_f32_16x16x32_bf16(al[mf], bh[g], acc[mf][g], 0, 0, 0);
#pragma unroll
    for (int mf = 0; mf < MF; ++mf)
#pragma unroll
      for (int g = 0; g < 3; ++g)
        acc[mf][g] = __builtin_amdgcn_mfma_f32_16x16x32_bf16(ah[mf], bl[g], acc[mf][g], 0, 0, 0);
  };

  // harvest hold[mf][r] = Ahi[m][col]+Alo[m][col] from the staged chunk (cc = col&31)
  auto HARVEST = [&](const unsigned short* tAh, const unsigned short* tAl){
    const int cc = col & 31;
#pragma unroll
    for (int mf = 0; mf < MF; ++mf)
#pragma unroll
      for (int r = 0; r < 4; ++r){
        const int row = wm*(MF*16) + mf*16 + kq*4 + r;
        const int a = (row*4 + ((cc>>3) ^ ((row>>1)&3)))*8 + (cc&7);
        hold[mf][r] = bf2f(tAh[a]) + bf2f(tAl[a]);
      }
  };

  STAGE(0, sAh0, sAl0, sBh0, sBl0);
  __syncthreads();                         // buf0 ready
  for (int q = 0; q < 8; ++q){
    STAGE(2*q+1, sAh1, sAl1, sBh1, sBl1);  // prefetch odd chunk into buf1
    COMPUTE(sAh0, sAl0, sBh0, sBl0);       // compute even chunk 2q from buf0
    if (gru && mychunk == 2*q) HARVEST(sAh0, sAl0);
    __syncthreads();                       // drains prefetch; buf1 ready
    if (q < 7) STAGE(2*q+2, sAh0, sAl0, sBh0, sBl0);
    COMPUTE(sAh1, sAl1, sBh1, sBl1);       // compute odd chunk 2q+1 from buf1
    if (gru && mychunk == 2*q+1) HARVEST(sAh1, sAl1);
    __syncthreads();
  }

  // epilogue. C/D frag: col = lane&15, row = (lane>>4)*4 + reg.
  if (!gru){
    const float b0f = bias[col], b1f = bias[512+col], b2f = bias[1024+col];
#pragma unroll
    for (int mf = 0; mf < MF; ++mf){
      const int mb = m0 + wm*(MF*16) + mf*16 + kq*4;
#pragma unroll
      for (int r = 0; r < 4; ++r){
        const int m = mb + r;
        if (m < M){
          float* c = OutF + (size_t)m*1536 + col;
          c[0]    = acc[mf][0][r] + b0f;
          c[512]  = acc[mf][1][r] + b1f;
          c[1024] = acc[mf][2][r] + b2f;
        }
      }
    }
  } else {
    const float br = bias[col], bz = bias[512+col], bn = bias[1024+col];
#pragma unroll
    for (int mf = 0; mf < MF; ++mf){
      const int mb = m0 + wm*(MF*16) + mf*16 + kq*4;
#pragma unroll
      for (int r = 0; r < 4; ++r){
        const int m = mb + r;
        if (m < M){
          const int gr = plink ? plink[m*6 + s] : m;
          const float* gi = GI + (size_t)gr*1536 + col;
          const size_t ix = (size_t)m*512 + col;
          float rr = sigp(gi[0]    + acc[mf][0][r] + br);
          float zz = sigp(gi[512]  + acc[mf][1][r] + bz);
          float nn = 2.f*sigp(2.f*(gi[1024] + rr*(acc[mf][2][r] + bn))) - 1.f; // tanh
          float h  = (1.f - zz)*nn + zz*hold[mf][r];
          unsigned short hh = f2bf(h);
          Ohi[ix] = hh;
          Olo[ix] = f2bf(h - bf2f(hh));
          if (writeF) OutF[ix] = h;
        }
      }
    }
  }
}

// ---------------- readout MFMA GEMM: C[M,N] = relu?(Apair @ Wpair^T + b) ----------------
// 256 threads = 4 waves (wm=wave>>1, wn=wave&1), wave tile 64x32 (mf=4, nf=2).
__global__ __launch_bounds__(256,3) void rgemm_k(
    const unsigned short* __restrict__ Ahi, const unsigned short* __restrict__ Alo,
    const unsigned short* __restrict__ Whi, const unsigned short* __restrict__ Wlo,
    const float* __restrict__ bias,
    float* __restrict__ OutF,
    unsigned short* __restrict__ Ohi, unsigned short* __restrict__ Olo,
    int M, int N, int K, int relu)
{
  __shared__ unsigned short rAh0[128*32], rAl0[128*32], rWh0[64*32], rWl0[64*32];
  __shared__ unsigned short rAh1[128*32], rAl1[128*32], rWh1[64*32], rWl1[64*32];
  const int tid = threadIdx.x;
  const int lane = tid & 63, wave = tid >> 6;
  const int wm = wave >> 1, wn = wave & 1;
  const int m0 = blockIdx.x * 128, n0 = blockIdx.y * 64;
  const int c16 = lane & 15, kq = lane >> 4;
  const int K2 = K*2;

  int offA0, offA1, offW;
  { int g = tid;      int row = g>>2; int kg=(g&3)^((row>>1)&3); offA0 = (m0+row)*K2 + kg*16; }
  { int g = tid+256;  int row = g>>2; int kg=(g&3)^((row>>1)&3); offA1 = (m0+row)*K2 + kg*16; }
  { int g = tid;      int v = g>>2;   int kg=(g&3)^((v>>1)&3);   offW  = (n0+v)*K2 + kg*16; }
  const int gA0 = (wave*64)*8, gA1 = (wave*64+256)*8;
  const int gW  = (wave*64)*8;

  const int rA = wm*64 + c16;
  const int rdA = (rA*4 + (kq ^ ((rA>>1)&3)))*8;
  const int vB = wn*32 + c16;
  const int rdB = (vB*4 + (kq ^ ((vB>>1)&3)))*8;

  float4v acc[4][2];
#pragma unroll
  for (int i = 0; i < 4; ++i)
#pragma unroll
    for (int j = 0; j < 2; ++j) acc[i][j] = (float4v){0.f,0.f,0.f,0.f};

  auto STAGE = [&](int kb, unsigned short* dAh, unsigned short* dAl,
                   unsigned short* dWh, unsigned short* dWl){
    const int kbb = kb*64;
    gload16((const char*)Ahi + kbb + offA0, dAh + gA0);
    gload16((const char*)Ahi + kbb + offA1, dAh + gA1);
    gload16((const char*)Alo + kbb + offA0, dAl + gA0);
    gload16((const char*)Alo + kbb + offA1, dAl + gA1);
    gload16((const char*)Whi + kbb + offW, dWh + gW);
    gload16((const char*)Wlo + kbb + offW, dWl + gW);
  };

  auto COMPUTE = [&](const unsigned short* tAh, const unsigned short* tAl,
                     const unsigned short* tWh, const unsigned short* tWl){
    short8v ah[4], al[4], bh[2], bl[2];
#pragma unroll
    for (int mf = 0; mf < 4; ++mf) ah[mf] = *(const short8v*)(tAh + rdA + mf*512);
#pragma unroll
    for (int nf = 0; nf < 2; ++nf) bh[nf] = *(const short8v*)(tWh + rdB + nf*512);
#pragma unroll
    for (int mf = 0; mf < 4; ++mf) al[mf] = *(const short8v*)(tAl + rdA + mf*512);
#pragma unroll
    for (int mf = 0; mf < 4; ++mf)
#pragma unroll
      for (int nf = 0; nf < 2; ++nf)
        acc[mf][nf] = __builtin_amdgcn_mfma_f32_16x16x32_bf16(ah[mf], bh[nf], acc[mf][nf], 0, 0, 0);
#pragma unroll
    for (int nf = 0; nf < 2; ++nf) bl[nf] = *(const short8v*)(tWl + rdB + nf*512);
#pragma unroll
    for (int mf = 0; mf < 4; ++mf)
#pragma unroll
      for (int nf = 0; nf < 2; ++nf)
        acc[mf][nf] = __builtin_amdgcn_mfma_f32_16x16x32_bf16(al[mf], bh[nf], acc[mf][nf], 0, 0, 0);
#pragma unroll
    for (int mf = 0; mf < 4; ++mf)
#pragma unroll
      for (int nf = 0; nf < 2; ++nf)
        acc[mf][nf] = __builtin_amdgcn_mfma_f32_16x16x32_bf16(ah[mf], bl[nf], acc[mf][nf], 0, 0, 0);
  };

  const int nc = K >> 5;                    // chunks of 32 (16 for K=512, 8 for K=256)
  STAGE(0, rAh0, rAl0, rWh0, rWl0);
  __syncthreads();
  for (int q = 0; q < (nc>>1); ++q){
    STAGE(2*q+1, rAh1, rAl1, rWh1, rWl1);
    COMPUTE(rAh0, rAl0, rWh0, rWl0);
    __syncthreads();
    if (q < (nc>>1)-1) STAGE(2*q+2, rAh0, rAl0, rWh0, rWl0);
    COMPUTE(rAh1, rAl1, rWh1, rWl1);
    __syncthreads();
  }

  // epilogue
#pragma unroll
  for (int nf = 0; nf < 2; ++nf){
    const int col = n0 + wn*32 + nf*16 + c16;
    const float b = bias[col];
#pragma unroll
    for (int mf = 0; mf < 4; ++mf){
      const int mb = m0 + wm*64 + mf*16 + kq*4;
#pragma unroll
      for (int r = 0; r < 4; ++r){
        const int m = mb + r;
        if (m < M){
          float v = acc[mf][nf][r] + b;
          if (relu) v = fmaxf(v, 0.f);
          const size_t ix = (size_t)m*N + col;
          if (OutF) OutF[ix] = v;
          if (Ohi){
            unsigned short hh = f2bf(v);
            Ohi[ix] = hh;
            Olo[ix] = f2bf(v - bf2f(hh));
          }
        }
      }
    }
  }
}

// ---------------- per-step segment-sum (u32-vectorized); emits hi/lo agg at s==5 ----------------
__global__ void aggv_k(const unsigned short* __restrict__ Hh, const unsigned short* __restrict__ Hl,
                       const int* __restrict__ plist,
                       const int* __restrict__ off, const int* __restrict__ cnt, int s,
                       float* __restrict__ AGG, int isFirst,
                       unsigned short* __restrict__ Ghi, unsigned short* __restrict__ Glo,
                       int emit)
{
  int l = blockIdx.x, t = threadIdx.x;        // thread t handles cols 2t, 2t+1
  size_t base = (size_t)l*512 + 2*t;
  if (l >= 2000){
    AGG[base] = 0.f; AGG[base+1] = 0.f;
    if (emit){ *(unsigned*)&Ghi[base] = 0u; *(unsigned*)&Glo[base] = 0u; }
    return;
  }
  int o = off[s*2000 + l], c = cnt[s*2000 + l];
  float a0 = isFirst ? 0.f : AGG[base];
  float a1 = isFirst ? 0.f : AGG[base+1];
  for (int i = 0; i < c; ++i){
    size_t p = (size_t)plist[o + i] * 512 + 2*t;
    unsigned hh = *(const unsigned*)(Hh + p);
    unsigned hl = *(const unsigned*)(Hl + p);
    a0 += __uint_as_float(hh << 16) + __uint_as_float(hl << 16);
    a1 += __uint_as_float(hh & 0xffff0000u) + __uint_as_float(hl & 0xffff0000u);
  }
  AGG[base] = a0; AGG[base+1] = a1;
  if (emit){
    unsigned short h0 = f2bf(a0), h1 = f2bf(a1);
    *(unsigned*)&Ghi[base] = (unsigned)h0 | ((unsigned)h1 << 16);
    unsigned short l0 = f2bf(a0 - bf2f(h0)), l1 = f2bf(a1 - bf2f(h1));
    *(unsigned*)&Glo[base] = (unsigned)l0 | ((unsigned)l1 << 16);
  }
}

// ---------------- final 128->1 dot per row ----------------
__global__ void dotf_k(const float* __restrict__ T2, const float* __restrict__ w3,
                       const float* __restrict__ b3, float* __restrict__ out, int M)
{
  int lane = threadIdx.x & 63, w = threadIdx.x >> 6;
  int m = blockIdx.x * 4 + w;
  if (m >= M) return;
  float s = T2[(size_t)m*128 + lane] * w3[lane]
          + T2[(size_t)m*128 + 64 + lane] * w3[64 + lane];
#pragma unroll
  for (int off = 32; off; off >>= 1) s += __shfl_xor(s, off);
  if (lane == 0) out[m] = s + b3[0];
}

extern "C" void kernel_launch(void* const* d_in, const int* in_sizes, int n_in,
                              void* d_out, int out_size, void* d_ws, size_t ws_size,
                              hipStream_t stream)
{
  const int*   links = (const int*)d_in[0];
  const int*   paths = (const int*)d_in[1];
  const int*   seqs  = (const int*)d_in[2];
  const float* cap   = (const float*)d_in[3];
  const float* bw    = (const float*)d_in[4];
  const float* Wih_p = (const float*)d_in[5];
  const float* Whh_p = (const float*)d_in[6];
  const float* bih_p = (const float*)d_in[7];
  const float* bhh_p = (const float*)d_in[8];
  const float* Wih_l = (const float*)d_in[9];
  const float* Whh_l = (const float*)d_in[10];
  const float* bih_l = (const float*)d_in[11];
  const float* bhh_l = (const float*)d_in[12];
  const float* d_w1 = (const float*)d_in[13]; const float* d_b1 = (const float*)d_in[14];
  const float* d_w2 = (const float*)d_in[15]; const float* d_b2 = (const float*)d_in[16];
  const float* d_w3 = (const float*)d_in[17]; const float* d_b3 = (const float*)d_in[18];
  const float* j_w1 = (const float*)d_in[19]; const float* j_b1 = (const float*)d_in[20];
  const float* j_w2 = (const float*)d_in[21]; const float* j_b2 = (const float*)d_in[22];
  const float* j_w3 = (const float*)d_in[23]; const float* j_b3 = (const float*)d_in[24];
  float* out = (float*)d_out;

  const int MpP = 20480;   // 160 * 128 (XCD mapping total: 20 m-blocks/XCD)
  const int MpL = 2048;    // 32 * 64 (4 m-blocks/XCD for the BM=64 link kernel)
  char* p = (char*)d_ws;
  auto alloc = [&](size_t n){ char* r = p; p += (n + 255) & ~(size_t)255; return r; };
  unsigned short* Phi[2]; unsigned short* Plo[2];
  Phi[0] = (unsigned short*)alloc((size_t)MpP*512*2);
  Plo[0] = (unsigned short*)alloc((size_t)MpP*512*2);
  Phi[1] = (unsigned short*)alloc((size_t)MpP*512*2);
  Plo[1] = (unsigned short*)alloc((size_t)MpP*512*2);
  unsigned short* Lhi[2]; unsigned short* Llo[2];
  Lhi[0] = (unsigned short*)alloc((size_t)MpL*512*2);
  Llo[0] = (unsigned short*)alloc((size_t)MpL*512*2);
  Lhi[1] = (unsigned short*)alloc((size_t)MpL*512*2);
  Llo[1] = (unsigned short*)alloc((size_t)MpL*512*2);
  float* LG  = (float*)alloc((size_t)MpL*1536*4);                // gi rows [2048,1536]
  float* AGG = (float*)alloc((size_t)MpL*512*4);
  unsigned short* AGh = (unsigned short*)alloc((size_t)MpL*512*2);
  unsigned short* AGl = (unsigned short*)alloc((size_t)MpL*512*2);
  unsigned short* WhhPh = (unsigned short*)alloc((size_t)1536*512*2);
  unsigned short* WhhPl = (unsigned short*)alloc((size_t)1536*512*2);
  unsigned short* WihPh = (unsigned short*)alloc((size_t)1536*512*2);
  unsigned short* WihPl = (unsigned short*)alloc((size_t)1536*512*2);
  unsigned short* WhhLh = (unsigned short*)alloc((size_t)1536*512*2);
  unsigned short* WhhLl = (unsigned short*)alloc((size_t)1536*512*2);
  unsigned short* WihLh = (unsigned short*)alloc((size_t)1536*512*2);
  unsigned short* WihLl = (unsigned short*)alloc((size_t)1536*512*2);
  unsigned short* DW1h = (unsigned short*)alloc((size_t)256*512*2);
  unsigned short* DW1l = (unsigned short*)alloc((size_t)256*512*2);
  unsigned short* DW2h = (unsigned short*)alloc((size_t)128*256*2);
  unsigned short* DW2l = (unsigned short*)alloc((size_t)128*256*2);
  unsigned short* JW1h = (unsigned short*)alloc((size_t)256*512*2);
  unsigned short* JW1l = (unsigned short*)alloc((size_t)256*512*2);
  unsigned short* JW2h = (unsigned short*)alloc((size_t)128*256*2);
  unsigned short* JW2l = (unsigned short*)alloc((size_t)128*256*2);
  int* cnt2  = (int*)alloc(12000*4);
  int* off2  = (int*)alloc(12000*4);
  int* cur2  = (int*)alloc(12000*4);
  int* plist = (int*)alloc(120000*4);
  int* plink = (int*)alloc(120000*4);
  // readout scratch aliases dead buffers after the loop (final state pair = Phi[0]/Plo[0]):
  unsigned short* t1h = Phi[1];   // [20096,256] bf16 -> 10.29 MB <= 20.97 MB
  unsigned short* t1l = Plo[1];
  float* t2 = LG;                 // [20032,128] fp32 -> 10.26 MB <= 12.58 MB
  if ((size_t)(p - (char*)d_ws) > ws_size){
    sentf_k<<<(out_size+255)/256,256,0,stream>>>(out, out_size, 0.25f);
    return;
  }

  hipMemsetAsync(cnt2, 0, 12000*4, stream);
  prep_k<<<469,256,0,stream>>>(links, paths, seqs, plink, cnt2);
  scan_k<<<1,256,0,stream>>>(cnt2, off2, cur2);
  fill2_k<<<469,256,0,stream>>>(links, paths, seqs, cur2, plist);
  wcvt_k<<<3072,256,0,stream>>>(Whh_p, WhhPh, WhhPl, 1536*512);
  wcvt_k<<<3072,256,0,stream>>>(Wih_p, WihPh, WihPl, 1536*512);
  wcvt_k<<<3072,256,0,stream>>>(Whh_l, WhhLh, WhhLl, 1536*512);
  wcvt_k<<<3072,256,0,stream>>>(Wih_l, WihLh, WihLl, 1536*512);
  wcvt_k<<<512,256,0,stream>>>(d_w1, DW1h, DW1l, 256*512);
  wcvt_k<<<128,256,0,stream>>>(d_w2, DW2h, DW2l, 128*256);
  wcvt_k<<<512,256,0,stream>>>(j_w1, JW1h, JW1l, 256*512);
  wcvt_k<<<128,256,0,stream>>>(j_w2, JW2h, JW2l, 128*256);
  initp_k<<<(MpP*512)/256,256,0,stream>>>(bw,  Phi[0], Plo[0], Phi[1], Plo[1], 20000);
  initp_k<<<(MpL*512)/256,256,0,stream>>>(cap, Lhi[0], Llo[0], Lhi[1], Llo[1], 2000);

  int pb = 0, lb = 0;
  for (int t = 0; t < 8; ++t) {
    // LG = link_h @ Wih_p^T + bih_p  (gi rows for path entries) -- BM=64, 256 blocks
    gmfma_t<2><<<32*8,512,0,stream>>>(Lhi[lb], Llo[lb], WihPh, WihPl, bih_p,
                                      (const float*)0, (const int*)0, 0,
                                      LG, (unsigned short*)0, (unsigned short*)0, 2000, 0, 0);
    for (int s6 = 0; s6 < 6; ++s6) {
      gmfma_t<4><<<160*8,512,0,stream>>>(Phi[pb], Plo[pb], WhhPh, WhhPl, bhh_p,
                                         LG, plink, s6,
                                         (float*)0, Phi[pb^1], Plo[pb^1], 20000, 1, 0);
      pb ^= 1;
      aggv_k<<<2048,256,0,stream>>>(Phi[pb], Plo[pb], plist, off2, cnt2, s6, AGG,
                                    (s6==0)?1:0, AGh, AGl, (s6==5)?1:0);
    }
    // GIL = agg @ Wih_l^T + bih_l (into LG); link_h = GRU(GIL, link_h) -- BM=64
    gmfma_t<2><<<32*8,512,0,stream>>>(AGh, AGl, WihLh, WihLl, bih_l,
                                      (const float*)0, (const int*)0, 0,
                                      LG, (unsigned short*)0, (unsigned short*)0, 2000, 0, 0);
    gmfma_t<2><<<32*8,512,0,stream>>>(Lhi[lb], Llo[lb], WhhLh, WhhLl, bhh_l,
                                      LG, (const int*)0, 0,
                                      (float*)0, Lhi[lb^1], Llo[lb^1], 2000, 1, 0);
    lb ^= 1;
  }
  // final state pair: pb flipped 48 times -> Phi[0]/Plo[0]

  // readout: delay (MFMA split-bf16; layer1 emits t1 pair, layer2 emits fp32 t2)
  rgemm_k<<<dim3(157,4),256,0,stream>>>(Phi[0], Plo[0], DW1h, DW1l, d_b1,
                                        (float*)0, t1h, t1l, 20000, 256, 512, 1);
  rgemm_k<<<dim3(157,2),256,0,stream>>>(t1h, t1l, DW2h, DW2l, d_b2,
                                        t2, (unsigned short*)0, (unsigned short*)0, 20000, 128, 256, 1);
  dotf_k<<<5000,256,0,stream>>>(t2, d_w3, d_b3, out, 20000);
  // readout: jitter
  rgemm_k<<<dim3(157,4),256,0,stream>>>(Phi[0], Plo[0], JW1h, JW1l, j_b1,
                                        (float*)0, t1h, t1l, 20000, 256, 512, 1);
  rgemm_k<<<dim3(157,2),256,0,stream>>>(t1h, t1l, JW2h, JW2l, j_b2,
                                        t2, (unsigned short*)0, (unsigned short*)0, 20000, 128, 256, 1);
  dotf_k<<<5000,256,0,stream>>>(t2, j_w3, j_b3, out + 20000, 20000);
}

// Round 13
// 6842.730 us; speedup vs baseline: 2.9422x; 1.4700x over previous
//
#include <hip/hip_runtime.h>
#include <stdint.h>

typedef __attribute__((ext_vector_type(4))) float float4v;
typedef __attribute__((ext_vector_type(8))) short short8v;   // 8 x bf16 (4 VGPRs)

static __device__ __forceinline__ float sigp(float x){ return 1.f/(1.f+expf(-x)); }

// fp32 -> bf16 (RNE) and back
static __device__ __forceinline__ unsigned short f2bf(float x){
  unsigned u = __float_as_uint(x);
  u += 0x7FFFu + ((u>>16)&1u);
  return (unsigned short)(u>>16);
}
static __device__ __forceinline__ float bf2f(unsigned short h){
  return __uint_as_float(((unsigned)h)<<16);
}

static __device__ __forceinline__ void gload16(const void* g, void* l){
  __builtin_amdgcn_global_load_lds((const __attribute__((address_space(1))) void*)g,
                                   (__attribute__((address_space(3))) void*)l, 16, 0, 0);
}

__global__ void sentf_k(float* __restrict__ o, int n, float v){
  int i = blockIdx.x*256 + threadIdx.x; if (i < n) o[i] = v;
}

// ---------------- prep: plink + histogram over (seq, link) ----------------
__global__ void prep_k(const int* __restrict__ links, const int* __restrict__ paths,
                       const int* __restrict__ seqs, int* __restrict__ plink,
                       int* __restrict__ cnt){
  int e = blockIdx.x*256 + threadIdx.x;
  if (e < 120000){
    int p = paths[e], s = seqs[e], l = links[e];
    plink[p*6 + s] = l;
    atomicAdd(&cnt[s*2000 + l], 1);
  }
}
__global__ void scan_k(const int* __restrict__ cnt, int* __restrict__ off, int* __restrict__ cur){
  __shared__ int part[256]; __shared__ int pref[256];
  int t = threadIdx.x;
  int lo = t*47, hi = lo+47; if (hi > 12000) hi = 12000;
  int s = 0;
  for (int i=lo;i<hi;i++) s += cnt[i];
  part[t] = s; __syncthreads();
  if (t==0){ int r=0; for (int i=0;i<256;i++){ pref[i]=r; r+=part[i]; } }
  __syncthreads();
  int r = pref[t];
  for (int i=lo;i<hi;i++){ off[i]=r; cur[i]=r; r+=cnt[i]; }
}
__global__ void fill2_k(const int* __restrict__ links, const int* __restrict__ paths,
                        const int* __restrict__ seqs, int* __restrict__ cur,
                        int* __restrict__ plist){
  int e = blockIdx.x*256 + threadIdx.x;
  if (e < 120000){
    int p = paths[e], s = seqs[e], l = links[e];
    int pos = atomicAdd(&cur[s*2000 + l], 1);
    plist[pos] = p;
  }
}

// ---------------- weight split: W -> (hi, lo) bf16 ----------------
__global__ void wcvt_k(const float* __restrict__ W, unsigned short* __restrict__ hi,
                       unsigned short* __restrict__ lo, int n){
  int i = blockIdx.x*256 + threadIdx.x;
  if (i < n){
    float x = W[i];
    unsigned short h = f2bf(x);
    hi[i] = h;
    lo[i] = f2bf(x - bf2f(h));
  }
}

// ---------------- state init: hi/lo pairs into both ping-pong buffers ----------------
__global__ void initp_k(const float* __restrict__ x0,
                        unsigned short* __restrict__ h0, unsigned short* __restrict__ l0,
                        unsigned short* __restrict__ h1, unsigned short* __restrict__ l1,
                        int Mreal){
  int i = blockIdx.x*256 + threadIdx.x;   // grid covers Mp*512
  int m = i >> 9, c = i & 511;
  float v = (c==0 && m < Mreal) ? x0[m] : 0.f;
  unsigned short hh = f2bf(v);
  unsigned short ll = f2bf(v - bf2f(hh));
  h0[i]=hh; l0[i]=ll; h1[i]=hh; l1[i]=ll;
}

// ---------------- MFMA split-bf16 GEMM, optionally fused GRU step ----------------
// (round-10 verified math; template MF sets BM = MF*32. NO hold-harvest — round 12's
// in-loop conditional hold[] spilled to scratch (+177 MB writes); epilogue reads the
// L2-hot state pair from global instead, as round 10 did.)
// C[M,1536] = A[M,512] @ W[1536,512]^T  via  Ahi@Whi + Alo@Whi + Ahi@Wlo
// tile: BM x 192; 512 threads = 8 waves (wm 0..1, wn 0..3), wave tile (MF*16) x 48.
// MF=4: path (BM=128, grid 160*8). MF=2: link (BM=64, grid 32*8 = 256 blocks,
// doubles link-side CU utilization; correctness verified in round 12).
// XCD-aware flat grid (HW: XCD = bid % 8): A-slice + W L2-shared by 8 cb-siblings.
// gru=0: OutF[m*1536 + gcol] = acc + bias[gcol]
// gru=1: fused gates; state hi/lo in (Ahi,Alo) -> (Ohi,Olo); fp32 out only if writeF.
template<int MF>
__global__ __launch_bounds__(512,4) void gmfma_t(
    const unsigned short* __restrict__ Ahi, const unsigned short* __restrict__ Alo,
    const unsigned short* __restrict__ Whi, const unsigned short* __restrict__ Wlo,
    const float* __restrict__ bias, const float* __restrict__ GI,
    const int* __restrict__ plink, int s,
    float* __restrict__ OutF,
    unsigned short* __restrict__ Ohi, unsigned short* __restrict__ Olo,
    int M, int gru, int writeF)
{
  __shared__ unsigned short sAh0[MF*1024], sAl0[MF*1024];
  __shared__ unsigned short sBh0[192*32], sBl0[192*32];
  __shared__ unsigned short sAh1[MF*1024], sAl1[MF*1024];
  __shared__ unsigned short sBh1[192*32], sBl1[192*32];
  const int tid  = threadIdx.x;
  const int lane = tid & 63, wave = tid >> 6;     // 0..7
  const int wm = wave >> 2, wn = wave & 3;        // wm 0..1, wn 0..3
  const int bid = blockIdx.x;
  const int X = bid & 7, kk2 = bid >> 3;
  const int m0 = ((kk2 >> 3)*8 + X) * (MF*32);
  const int cb = kk2 & 7;
  const int c16 = lane & 15, kq = lane >> 4;

  // A staging: MF*128 granules, one per thread (threads >= MF*128 skip).
  // LDS granule g holds global granule (row=g>>2, kg=(g&3)^((row>>1)&3)) via
  // pre-swizzled SOURCE address.
  int offA = 0;
  if (tid < MF*128){
    int row = tid >> 2; int kg = (tid & 3) ^ ((row >> 1) & 3);
    offA = (m0 + row)*1024 + kg*16;
  }
  // B staging: 768 granules; thread tid takes granule tid, tid<256 also 512+tid.
  // tile col v = wn_*48 + g*16 + c  ->  W row g*512 + cb*64 + wn_*16 + c.
  int offB0, offB1;
  {
    int gb = tid;
    int v  = gb >> 2;
    int kg = (gb & 3) ^ ((v >> 1) & 3);
    int wn_ = v / 48; int rem = v - wn_*48;
    int gg = rem >> 4, cc = rem & 15;
    offB0 = (gg*512 + cb*64 + wn_*16 + cc)*1024 + kg*16;
    gb = 512 + tid;                    // only meaningful for tid < 256
    v  = gb >> 2;
    kg = (gb & 3) ^ ((v >> 1) & 3);
    int wn2 = v / 48; rem = v - wn2*48;
    gg = rem >> 4; cc = rem & 15;
    if (wn2 > 3) wn2 = 3;
    offB1 = (gg*512 + cb*64 + wn2*16 + cc)*1024 + kg*16;
  }
  const int gA  = (wave*64)*8;
  const int gB0 = (wave*64)*8, gB1 = (512 + wave*64)*8;

  // ds_read base offsets (shorts); swizzle bits invariant under 16-row/col frag steps
  const int rA = wm*(MF*16) + c16;
  const int rdA = (rA*4 + (kq ^ ((rA>>1)&3)))*8;
  const int vB = wn*48 + c16;
  const int rdB = (vB*4 + (kq ^ ((vB>>1)&3)))*8;

  float4v acc[MF][3];
#pragma unroll
  for (int i = 0; i < MF; ++i)
#pragma unroll
    for (int j = 0; j < 3; ++j) acc[i][j] = (float4v){0.f,0.f,0.f,0.f};

  auto STAGE = [&](int kb, unsigned short* dAh, unsigned short* dAl,
                   unsigned short* dBh, unsigned short* dBl){
    const int kbb = kb*64;                 // 32 k-elems * 2B
    const char* ah = (const char*)Ahi + kbb;
    const char* al = (const char*)Alo + kbb;
    const char* wh = (const char*)Whi + kbb;
    const char* wl = (const char*)Wlo + kbb;
    if (tid < MF*128){
      gload16(ah + offA, dAh + gA);
      gload16(al + offA, dAl + gA);
    }
    gload16(wh + offB0, dBh + gB0);
    gload16(wl + offB0, dBl + gB0);
    if (tid < 256){                        // wave-uniform (waves 0..3)
      gload16(wh + offB1, dBh + gB1);
      gload16(wl + offB1, dBl + gB1);
    }
  };

  auto COMPUTE = [&](const unsigned short* tAh, const unsigned short* tAl,
                     const unsigned short* tBh, const unsigned short* tBl){
    short8v ah[MF], al[MF], bh[3], bl[3];
#pragma unroll
    for (int mf = 0; mf < MF; ++mf) ah[mf] = *(const short8v*)(tAh + rdA + mf*512);
#pragma unroll
    for (int g = 0; g < 3; ++g)  bh[g]  = *(const short8v*)(tBh + rdB + g*512);
#pragma unroll
    for (int mf = 0; mf < MF; ++mf) al[mf] = *(const short8v*)(tAl + rdA + mf*512);
#pragma unroll
    for (int mf = 0; mf < MF; ++mf)
#pragma unroll
      for (int g = 0; g < 3; ++g)
        acc[mf][g] = __builtin_amdgcn_mfma_f32_16x16x32_bf16(ah[mf], bh[g], acc[mf][g], 0, 0, 0);
#pragma unroll
    for (int g = 0; g < 3; ++g)  bl[g]  = *(const short8v*)(tBl + rdB + g*512);
#pragma unroll
    for (int mf = 0; mf < MF; ++mf)
#pragma unroll
      for (int g = 0; g < 3; ++g)
        acc[mf][g] = __builtin_amdgcn_mfma_f32_16x16x32_bf16(al[mf], bh[g], acc[mf][g], 0, 0, 0);
#pragma unroll
    for (int mf = 0; mf < MF; ++mf)
#pragma unroll
      for (int g = 0; g < 3; ++g)
        acc[mf][g] = __builtin_amdgcn_mfma_f32_16x16x32_bf16(ah[mf], bl[g], acc[mf][g], 0, 0, 0);
  };

  STAGE(0, sAh0, sAl0, sBh0, sBl0);
  __syncthreads();                         // buf0 ready
  for (int q = 0; q < 8; ++q){
    STAGE(2*q+1, sAh1, sAl1, sBh1, sBl1);  // prefetch odd chunk into buf1
    COMPUTE(sAh0, sAl0, sBh0, sBl0);       // compute even chunk from buf0
    __syncthreads();                       // drains prefetch; buf1 ready
    if (q < 7) STAGE(2*q+2, sAh0, sAl0, sBh0, sBl0);
    COMPUTE(sAh1, sAl1, sBh1, sBl1);
    __syncthreads();
  }

  // epilogue. C/D frag: col = lane&15, row = (lane>>4)*4 + reg.
  const int col = cb*64 + wn*16 + c16;
  if (!gru){
    const float b0f = bias[col], b1f = bias[512+col], b2f = bias[1024+col];
#pragma unroll
    for (int mf = 0; mf < MF; ++mf){
      const int mb = m0 + wm*(MF*16) + mf*16 + kq*4;
#pragma unroll
      for (int r = 0; r < 4; ++r){
        const int m = mb + r;
        if (m < M){
          float* c = OutF + (size_t)m*1536 + col;
          c[0]    = acc[mf][0][r] + b0f;
          c[512]  = acc[mf][1][r] + b1f;
          c[1024] = acc[mf][2][r] + b2f;
        }
      }
    }
  } else {
    const float br = bias[col], bz = bias[512+col], bn = bias[1024+col];
#pragma unroll
    for (int mf = 0; mf < MF; ++mf){
      const int mb = m0 + wm*(MF*16) + mf*16 + kq*4;
#pragma unroll
      for (int r = 0; r < 4; ++r){
        const int m = mb + r;
        if (m < M){
          const int gr = plink ? plink[m*6 + s] : m;
          const float* gi = GI + (size_t)gr*1536 + col;
          const size_t ix = (size_t)m*512 + col;
          float hold = bf2f(Ahi[ix]) + bf2f(Alo[ix]);
          float rr = sigp(gi[0]    + acc[mf][0][r] + br);
          float zz = sigp(gi[512]  + acc[mf][1][r] + bz);
          float nn = 2.f*sigp(2.f*(gi[1024] + rr*(acc[mf][2][r] + bn))) - 1.f; // tanh
          float h  = (1.f - zz)*nn + zz*hold;
          unsigned short hh = f2bf(h);
          Ohi[ix] = hh;
          Olo[ix] = f2bf(h - bf2f(hh));
          if (writeF) OutF[ix] = h;
        }
      }
    }
  }
}

// ---------------- readout MFMA GEMM: C[M,N] = relu?(Apair @ Wpair^T + b) ----------------
// 256 threads = 4 waves (wm=wave>>1, wn=wave&1), wave tile 64x32 (mf=4, nf=2).
__global__ __launch_bounds__(256,3) void rgemm_k(
    const unsigned short* __restrict__ Ahi, const unsigned short* __restrict__ Alo,
    const unsigned short* __restrict__ Whi, const unsigned short* __restrict__ Wlo,
    const float* __restrict__ bias,
    float* __restrict__ OutF,
    unsigned short* __restrict__ Ohi, unsigned short* __restrict__ Olo,
    int M, int N, int K, int relu)
{
  __shared__ unsigned short rAh0[128*32], rAl0[128*32], rWh0[64*32], rWl0[64*32];
  __shared__ unsigned short rAh1[128*32], rAl1[128*32], rWh1[64*32], rWl1[64*32];
  const int tid = threadIdx.x;
  const int lane = tid & 63, wave = tid >> 6;
  const int wm = wave >> 1, wn = wave & 1;
  const int m0 = blockIdx.x * 128, n0 = blockIdx.y * 64;
  const int c16 = lane & 15, kq = lane >> 4;
  const int K2 = K*2;

  int offA0, offA1, offW;
  { int g = tid;      int row = g>>2; int kg=(g&3)^((row>>1)&3); offA0 = (m0+row)*K2 + kg*16; }
  { int g = tid+256;  int row = g>>2; int kg=(g&3)^((row>>1)&3); offA1 = (m0+row)*K2 + kg*16; }
  { int g = tid;      int v = g>>2;   int kg=(g&3)^((v>>1)&3);   offW  = (n0+v)*K2 + kg*16; }
  const int gA0 = (wave*64)*8, gA1 = (wave*64+256)*8;
  const int gW  = (wave*64)*8;

  const int rA = wm*64 + c16;
  const int rdA = (rA*4 + (kq ^ ((rA>>1)&3)))*8;
  const int vB = wn*32 + c16;
  const int rdB = (vB*4 + (kq ^ ((vB>>1)&3)))*8;

  float4v acc[4][2];
#pragma unroll
  for (int i = 0; i < 4; ++i)
#pragma unroll
    for (int j = 0; j < 2; ++j) acc[i][j] = (float4v){0.f,0.f,0.f,0.f};

  auto STAGE = [&](int kb, unsigned short* dAh, unsigned short* dAl,
                   unsigned short* dWh, unsigned short* dWl){
    const int kbb = kb*64;
    gload16((const char*)Ahi + kbb + offA0, dAh + gA0);
    gload16((const char*)Ahi + kbb + offA1, dAh + gA1);
    gload16((const char*)Alo + kbb + offA0, dAl + gA0);
    gload16((const char*)Alo + kbb + offA1, dAl + gA1);
    gload16((const char*)Whi + kbb + offW, dWh + gW);
    gload16((const char*)Wlo + kbb + offW, dWl + gW);
  };

  auto COMPUTE = [&](const unsigned short* tAh, const unsigned short* tAl,
                     const unsigned short* tWh, const unsigned short* tWl){
    short8v ah[4], al[4], bh[2], bl[2];
#pragma unroll
    for (int mf = 0; mf < 4; ++mf) ah[mf] = *(const short8v*)(tAh + rdA + mf*512);
#pragma unroll
    for (int nf = 0; nf < 2; ++nf) bh[nf] = *(const short8v*)(tWh + rdB + nf*512);
#pragma unroll
    for (int mf = 0; mf < 4; ++mf) al[mf] = *(const short8v*)(tAl + rdA + mf*512);
#pragma unroll
    for (int mf = 0; mf < 4; ++mf)
#pragma unroll
      for (int nf = 0; nf < 2; ++nf)
        acc[mf][nf] = __builtin_amdgcn_mfma_f32_16x16x32_bf16(ah[mf], bh[nf], acc[mf][nf], 0, 0, 0);
#pragma unroll
    for (int nf = 0; nf < 2; ++nf) bl[nf] = *(const short8v*)(tWl + rdB + nf*512);
#pragma unroll
    for (int mf = 0; mf < 4; ++mf)
#pragma unroll
      for (int nf = 0; nf < 2; ++nf)
        acc[mf][nf] = __builtin_amdgcn_mfma_f32_16x16x32_bf16(al[mf], bh[nf], acc[mf][nf], 0, 0, 0);
#pragma unroll
    for (int mf = 0; mf < 4; ++mf)
#pragma unroll
      for (int nf = 0; nf < 2; ++nf)
        acc[mf][nf] = __builtin_amdgcn_mfma_f32_16x16x32_bf16(ah[mf], bl[nf], acc[mf][nf], 0, 0, 0);
  };

  const int nc = K >> 5;                    // chunks of 32 (16 for K=512, 8 for K=256)
  STAGE(0, rAh0, rAl0, rWh0, rWl0);
  __syncthreads();
  for (int q = 0; q < (nc>>1); ++q){
    STAGE(2*q+1, rAh1, rAl1, rWh1, rWl1);
    COMPUTE(rAh0, rAl0, rWh0, rWl0);
    __syncthreads();
    if (q < (nc>>1)-1) STAGE(2*q+2, rAh0, rAl0, rWh0, rWl0);
    COMPUTE(rAh1, rAl1, rWh1, rWl1);
    __syncthreads();
  }

  // epilogue
#pragma unroll
  for (int nf = 0; nf < 2; ++nf){
    const int col = n0 + wn*32 + nf*16 + c16;
    const float b = bias[col];
#pragma unroll
    for (int mf = 0; mf < 4; ++mf){
      const int mb = m0 + wm*64 + mf*16 + kq*4;
#pragma unroll
      for (int r = 0; r < 4; ++r){
        const int m = mb + r;
        if (m < M){
          float v = acc[mf][nf][r] + b;
          if (relu) v = fmaxf(v, 0.f);
          const size_t ix = (size_t)m*N + col;
          if (OutF) OutF[ix] = v;
          if (Ohi){
            unsigned short hh = f2bf(v);
            Ohi[ix] = hh;
            Olo[ix] = f2bf(v - bf2f(hh));
          }
        }
      }
    }
  }
}

// ---------------- per-step segment-sum (u32-vectorized); emits hi/lo agg at s==5 ----------------
__global__ void aggv_k(const unsigned short* __restrict__ Hh, const unsigned short* __restrict__ Hl,
                       const int* __restrict__ plist,
                       const int* __restrict__ off, const int* __restrict__ cnt, int s,
                       float* __restrict__ AGG, int isFirst,
                       unsigned short* __restrict__ Ghi, unsigned short* __restrict__ Glo,
                       int emit)
{
  int l = blockIdx.x, t = threadIdx.x;        // thread t handles cols 2t, 2t+1
  size_t base = (size_t)l*512 + 2*t;
  if (l >= 2000){
    AGG[base] = 0.f; AGG[base+1] = 0.f;
    if (emit){ *(unsigned*)&Ghi[base] = 0u; *(unsigned*)&Glo[base] = 0u; }
    return;
  }
  int o = off[s*2000 + l], c = cnt[s*2000 + l];
  float a0 = isFirst ? 0.f : AGG[base];
  float a1 = isFirst ? 0.f : AGG[base+1];
  for (int i = 0; i < c; ++i){
    size_t p = (size_t)plist[o + i] * 512 + 2*t;
    unsigned hh = *(const unsigned*)(Hh + p);
    unsigned hl = *(const unsigned*)(Hl + p);
    a0 += __uint_as_float(hh << 16) + __uint_as_float(hl << 16);
    a1 += __uint_as_float(hh & 0xffff0000u) + __uint_as_float(hl & 0xffff0000u);
  }
  AGG[base] = a0; AGG[base+1] = a1;
  if (emit){
    unsigned short h0 = f2bf(a0), h1 = f2bf(a1);
    *(unsigned*)&Ghi[base] = (unsigned)h0 | ((unsigned)h1 << 16);
    unsigned short l0 = f2bf(a0 - bf2f(h0)), l1 = f2bf(a1 - bf2f(h1));
    *(unsigned*)&Glo[base] = (unsigned)l0 | ((unsigned)l1 << 16);
  }
}

// ---------------- final 128->1 dot per row ----------------
__global__ void dotf_k(const float* __restrict__ T2, const float* __restrict__ w3,
                       const float* __restrict__ b3, float* __restrict__ out, int M)
{
  int lane = threadIdx.x & 63, w = threadIdx.x >> 6;
  int m = blockIdx.x * 4 + w;
  if (m >= M) return;
  float s = T2[(size_t)m*128 + lane] * w3[lane]
          + T2[(size_t)m*128 + 64 + lane] * w3[64 + lane];
#pragma unroll
  for (int off = 32; off; off >>= 1) s += __shfl_xor(s, off);
  if (lane == 0) out[m] = s + b3[0];
}

extern "C" void kernel_launch(void* const* d_in, const int* in_sizes, int n_in,
                              void* d_out, int out_size, void* d_ws, size_t ws_size,
                              hipStream_t stream)
{
  const int*   links = (const int*)d_in[0];
  const int*   paths = (const int*)d_in[1];
  const int*   seqs  = (const int*)d_in[2];
  const float* cap   = (const float*)d_in[3];
  const float* bw    = (const float*)d_in[4];
  const float* Wih_p = (const float*)d_in[5];
  const float* Whh_p = (const float*)d_in[6];
  const float* bih_p = (const float*)d_in[7];
  const float* bhh_p = (const float*)d_in[8];
  const float* Wih_l = (const float*)d_in[9];
  const float* Whh_l = (const float*)d_in[10];
  const float* bih_l = (const float*)d_in[11];
  const float* bhh_l = (const float*)d_in[12];
  const float* d_w1 = (const float*)d_in[13]; const float* d_b1 = (const float*)d_in[14];
  const float* d_w2 = (const float*)d_in[15]; const float* d_b2 = (const float*)d_in[16];
  const float* d_w3 = (const float*)d_in[17]; const float* d_b3 = (const float*)d_in[18];
  const float* j_w1 = (const float*)d_in[19]; const float* j_b1 = (const float*)d_in[20];
  const float* j_w2 = (const float*)d_in[21]; const float* j_b2 = (const float*)d_in[22];
  const float* j_w3 = (const float*)d_in[23]; const float* j_b3 = (const float*)d_in[24];
  float* out = (float*)d_out;

  const int MpP = 20480;   // 160 * 128 (XCD mapping total: 20 m-blocks/XCD)
  const int MpL = 2048;    // 32 * 64 (4 m-blocks/XCD for the BM=64 link kernel)
  char* p = (char*)d_ws;
  auto alloc = [&](size_t n){ char* r = p; p += (n + 255) & ~(size_t)255; return r; };
  unsigned short* Phi[2]; unsigned short* Plo[2];
  Phi[0] = (unsigned short*)alloc((size_t)MpP*512*2);
  Plo[0] = (unsigned short*)alloc((size_t)MpP*512*2);
  Phi[1] = (unsigned short*)alloc((size_t)MpP*512*2);
  Plo[1] = (unsigned short*)alloc((size_t)MpP*512*2);
  unsigned short* Lhi[2]; unsigned short* Llo[2];
  Lhi[0] = (unsigned short*)alloc((size_t)MpL*512*2);
  Llo[0] = (unsigned short*)alloc((size_t)MpL*512*2);
  Lhi[1] = (unsigned short*)alloc((size_t)MpL*512*2);
  Llo[1] = (unsigned short*)alloc((size_t)MpL*512*2);
  float* LG  = (float*)alloc((size_t)MpL*1536*4);                // gi rows [2048,1536]
  float* AGG = (float*)alloc((size_t)MpL*512*4);
  unsigned short* AGh = (unsigned short*)alloc((size_t)MpL*512*2);
  unsigned short* AGl = (unsigned short*)alloc((size_t)MpL*512*2);
  unsigned short* WhhPh = (unsigned short*)alloc((size_t)1536*512*2);
  unsigned short* WhhPl = (unsigned short*)alloc((size_t)1536*512*2);
  unsigned short* WihPh = (unsigned short*)alloc((size_t)1536*512*2);
  unsigned short* WihPl = (unsigned short*)alloc((size_t)1536*512*2);
  unsigned short* WhhLh = (unsigned short*)alloc((size_t)1536*512*2);
  unsigned short* WhhLl = (unsigned short*)alloc((size_t)1536*512*2);
  unsigned short* WihLh = (unsigned short*)alloc((size_t)1536*512*2);
  unsigned short* WihLl = (unsigned short*)alloc((size_t)1536*512*2);
  unsigned short* DW1h = (unsigned short*)alloc((size_t)256*512*2);
  unsigned short* DW1l = (unsigned short*)alloc((size_t)256*512*2);
  unsigned short* DW2h = (unsigned short*)alloc((size_t)128*256*2);
  unsigned short* DW2l = (unsigned short*)alloc((size_t)128*256*2);
  unsigned short* JW1h = (unsigned short*)alloc((size_t)256*512*2);
  unsigned short* JW1l = (unsigned short*)alloc((size_t)256*512*2);
  unsigned short* JW2h = (unsigned short*)alloc((size_t)128*256*2);
  unsigned short* JW2l = (unsigned short*)alloc((size_t)128*256*2);
  int* cnt2  = (int*)alloc(12000*4);
  int* off2  = (int*)alloc(12000*4);
  int* cur2  = (int*)alloc(12000*4);
  int* plist = (int*)alloc(120000*4);
  int* plink = (int*)alloc(120000*4);
  // readout scratch aliases dead buffers after the loop (final state pair = Phi[0]/Plo[0]):
  unsigned short* t1h = Phi[1];   // [20096,256] bf16 -> 10.29 MB <= 20.97 MB
  unsigned short* t1l = Plo[1];
  float* t2 = LG;                 // [20032,128] fp32 -> 10.26 MB <= 12.58 MB
  if ((size_t)(p - (char*)d_ws) > ws_size){
    sentf_k<<<(out_size+255)/256,256,0,stream>>>(out, out_size, 0.25f);
    return;
  }

  hipMemsetAsync(cnt2, 0, 12000*4, stream);
  prep_k<<<469,256,0,stream>>>(links, paths, seqs, plink, cnt2);
  scan_k<<<1,256,0,stream>>>(cnt2, off2, cur2);
  fill2_k<<<469,256,0,stream>>>(links, paths, seqs, cur2, plist);
  wcvt_k<<<3072,256,0,stream>>>(Whh_p, WhhPh, WhhPl, 1536*512);
  wcvt_k<<<3072,256,0,stream>>>(Wih_p, WihPh, WihPl, 1536*512);
  wcvt_k<<<3072,256,0,stream>>>(Whh_l, WhhLh, WhhLl, 1536*512);
  wcvt_k<<<3072,256,0,stream>>>(Wih_l, WihLh, WihLl, 1536*512);
  wcvt_k<<<512,256,0,stream>>>(d_w1, DW1h, DW1l, 256*512);
  wcvt_k<<<128,256,0,stream>>>(d_w2, DW2h, DW2l, 128*256);
  wcvt_k<<<512,256,0,stream>>>(j_w1, JW1h, JW1l, 256*512);
  wcvt_k<<<128,256,0,stream>>>(j_w2, JW2h, JW2l, 128*256);
  initp_k<<<(MpP*512)/256,256,0,stream>>>(bw,  Phi[0], Plo[0], Phi[1], Plo[1], 20000);
  initp_k<<<(MpL*512)/256,256,0,stream>>>(cap, Lhi[0], Llo[0], Lhi[1], Llo[1], 2000);

  int pb = 0, lb = 0;
  for (int t = 0; t < 8; ++t) {
    // LG = link_h @ Wih_p^T + bih_p  (gi rows for path entries) -- BM=64, 256 blocks
    gmfma_t<2><<<32*8,512,0,stream>>>(Lhi[lb], Llo[lb], WihPh, WihPl, bih_p,
                                      (const float*)0, (const int*)0, 0,
                                      LG, (unsigned short*)0, (unsigned short*)0, 2000, 0, 0);
    for (int s6 = 0; s6 < 6; ++s6) {
      gmfma_t<4><<<160*8,512,0,stream>>>(Phi[pb], Plo[pb], WhhPh, WhhPl, bhh_p,
                                         LG, plink, s6,
                                         (float*)0, Phi[pb^1], Plo[pb^1], 20000, 1, 0);
      pb ^= 1;
      aggv_k<<<2048,256,0,stream>>>(Phi[pb], Plo[pb], plist, off2, cnt2, s6, AGG,
                                    (s6==0)?1:0, AGh, AGl, (s6==5)?1:0);
    }
    // GIL = agg @ Wih_l^T + bih_l (into LG); link_h = GRU(GIL, link_h) -- BM=64
    gmfma_t<2><<<32*8,512,0,stream>>>(AGh, AGl, WihLh, WihLl, bih_l,
                                      (const float*)0, (const int*)0, 0,
                                      LG, (unsigned short*)0, (unsigned short*)0, 2000, 0, 0);
    gmfma_t<2><<<32*8,512,0,stream>>>(Lhi[lb], Llo[lb], WhhLh, WhhLl, bhh_l,
                                      LG, (const int*)0, 0,
                                      (float*)0, Lhi[lb^1], Llo[lb^1], 2000, 1, 0);
    lb ^= 1;
  }
  // final state pair: pb flipped 48 times -> Phi[0]/Plo[0]

  // readout: delay (MFMA split-bf16; layer1 emits t1 pair, layer2 emits fp32 t2)
  rgemm_k<<<dim3(157,4),256,0,stream>>>(Phi[0], Plo[0], DW1h, DW1l, d_b1,
                                        (float*)0, t1h, t1l, 20000, 256, 512, 1);
  rgemm_k<<<dim3(157,2),256,0,stream>>>(t1h, t1l, DW2h, DW2l, d_b2,
                                        t2, (unsigned short*)0, (unsigned short*)0, 20000, 128, 256, 1);
  dotf_k<<<5000,256,0,stream>>>(t2, d_w3, d_b3, out, 20000);
  // readout: jitter
  rgemm_k<<<dim3(157,4),256,0,stream>>>(Phi[0], Plo[0], JW1h, JW1l, j_b1,
                                        (float*)0, t1h, t1l, 20000, 256, 512, 1);
  rgemm_k<<<dim3(157,2),256,0,stream>>>(t1h, t1l, JW2h, JW2l, j_b2,
                                        t2, (unsigned short*)0, (unsigned short*)0, 20000, 128, 256, 1);
  dotf_k<<<5000,256,0,stream>>>(t2, j_w3, j_b3, out + 20000, 20000);
}